// Round 2
// baseline (76.395 us; speedup 1.0000x reference)
//
#include <hip/hip_runtime.h>
#include <stdint.h>

// Problem constants: B=8, C=256, K=64, T=1000
constexpr int Bn  = 8;
constexpr int Cn  = 256;
constexpr int Kn  = 64;
constexpr int Tn  = 1000;
constexpr int CH  = 32;    // t per block (T padded to 1024)
constexpr int NCH = 32;    // chunks per b

constexpr int XT_P = 264;  // xT[t][c]  bf16 pitch (rows 16B-aligned)
constexpr int XC_P = 40;   // xc[c][t]  bf16 pitch (rows 16B-aligned)
constexpr int MW_P = 33;   // Mw[k][t]  f32 pitch (bank-friendly)
constexpr int WL_P = 40;   // wl[k][t]  bf16 pitch

typedef float f32x4 __attribute__((ext_vector_type(4)));
typedef __bf16 bf16x8 __attribute__((ext_vector_type(8)));

__device__ __forceinline__ unsigned short f2bf(float f) {
    unsigned u = __float_as_uint(f);
    return (unsigned short)((u + 0x7FFFu + ((u >> 16) & 1u)) >> 16);  // RNE
}

union BF8 { unsigned short u[8]; bf16x8 v; };

// ---------------------------------------------------------------------------
// Fused weights + pool: grid (b x 32 chunks of 32t) = 256 blocks, 512 thr
// (8 waves, ~1 block/CU). Static LDS = 61.8 KB (< 64 KB limit). Per block:
//   stage: all 8 waves stage x f32->bf16 into xT[t][c] AND xc[c][t]
//          (+ exact fp32 xsq partials from the same registers).
//   M-GEMM: wave -> (k-tile = wave>>1, t-tile = wave&1).
//          A-operand: codes fp32 direct from global in fragment order
//          (L2-resident, verified pattern), bf16 in-register; exact fp32
//          csq[k] accumulated on the way + shfl reduce.
//   softmax over k (lane = k), fp32; w -> wl bf16 (LDS only) + Sp.
//   pool: one mfma 16x16x32 contracts the whole 32-t chunk per 16x16 tile:
//         part[b,ch,k,c] = sum_t w[k,t] x[c,t].
// ---------------------------------------------------------------------------
__global__ __launch_bounds__(512, 2) void lde_wp(
    const float* __restrict__ x,            // (B, C, T)
    const float* __restrict__ codes,        // (C, K)
    const float* __restrict__ scales,       // (K)
    float* __restrict__ part,               // (B, NCH, K, C)
    float* __restrict__ Sp)                 // (B, K, NCH)
{
    __shared__ __align__(16) unsigned short xT[CH * XT_P];   // 16896 B
    __shared__ __align__(16) unsigned short xc[Cn * XC_P];   // 20480 B
    __shared__ __align__(16) unsigned short wl[Kn * WL_P];   //  5120 B
    __shared__ float Mw[Kn * MW_P];                          //  8448 B
    __shared__ float xsqp[64 * 33];                          //  8448 B
    __shared__ float xsq[CH];                                //   128 B
    __shared__ float csqs[Kn];                               //   256 B
    __shared__ float spw[8 * 64];                            //  2048 B

    const int tid  = threadIdx.x;
    const int wave = tid >> 6;
    const int lane = tid & 63;
    const int n    = lane & 15;
    const int q    = lane >> 4;
    const int b    = blockIdx.x >> 5;
    const int ch   = blockIdx.x & 31;
    const int t0   = ch * CH;
    const float sc = scales[lane];           // lane = k in softmax phase

    // --- x staging: 512 threads, thread = (cg, tf); c = cg + 64r ---
    {
        const int tf = tid & 7;              // t-quad: t = t0 + 4*tf + i
        const int cg = tid >> 3;             // 0..63
        const float* xb = x + (size_t)b * Cn * Tn;
        float s0 = 0.f, s1 = 0.f, s2 = 0.f, s3 = 0.f;
        const int t = t0 + 4 * tf;
#pragma unroll
        for (int r = 0; r < 4; ++r) {
            int c = cg + 64 * r;
            float4 v;
            if (t + 3 < Tn) {
                v = *(const float4*)(xb + (size_t)c * Tn + t);
            } else {
                v.x = (t     < Tn) ? xb[(size_t)c * Tn + t]     : 0.f;
                v.y = (t + 1 < Tn) ? xb[(size_t)c * Tn + t + 1] : 0.f;
                v.z = (t + 2 < Tn) ? xb[(size_t)c * Tn + t + 2] : 0.f;
                v.w = (t + 3 < Tn) ? xb[(size_t)c * Tn + t + 3] : 0.f;
            }
            unsigned short h0 = f2bf(v.x), h1 = f2bf(v.y);
            unsigned short h2 = f2bf(v.z), h3 = f2bf(v.w);
            xT[(4 * tf + 0) * XT_P + c] = h0;
            xT[(4 * tf + 1) * XT_P + c] = h1;
            xT[(4 * tf + 2) * XT_P + c] = h2;
            xT[(4 * tf + 3) * XT_P + c] = h3;
            *(ushort4*)(xc + c * XC_P + 4 * tf) = make_ushort4(h0, h1, h2, h3);
            s0 = fmaf(v.x, v.x, s0);
            s1 = fmaf(v.y, v.y, s1);
            s2 = fmaf(v.z, v.z, s2);
            s3 = fmaf(v.w, v.w, s3);
        }
        float* xp = xsqp + cg * 33 + 4 * tf;
        xp[0] = s0; xp[1] = s1; xp[2] = s2; xp[3] = s3;
    }
    __syncthreads();

    // --- exact fp32 xsq[t] reduction (wave 0 front; overlaps M-GEMM) ---
    if (tid < 32) {
        float a = 0.f;
#pragma unroll
        for (int g = 0; g < 64; ++g) a += xsqp[g * 33 + tid];
        xsq[tid] = a;
    }

    // --- M-GEMM: wave -> (k-tile = wave>>1, t-tile = wave&1) ---
    {
        const int kt    = wave >> 1;
        const int tt    = wave & 1;
        const int kglob = kt * 16 + n;
        const float* cod = codes + (size_t)(q * 8) * Kn + kglob;  // codes[c][k]
        float csq_part = 0.f;
        f32x4 acc = {0.f, 0.f, 0.f, 0.f};
#pragma unroll
        for (int c0 = 0; c0 < Cn; c0 += 32) {
            float cf[8];
#pragma unroll
            for (int j = 0; j < 8; ++j) cf[j] = cod[(size_t)(c0 + j) * Kn];
            BF8 aF;
#pragma unroll
            for (int j = 0; j < 8; ++j) {
                csq_part = fmaf(cf[j], cf[j], csq_part);
                aF.u[j] = f2bf(cf[j]);
            }
            bf16x8 bF = *(const bf16x8*)(xT + (tt * 16 + n) * XT_P + c0 + q * 8);
            acc = __builtin_amdgcn_mfma_f32_16x16x32_bf16(aF.v, bF, acc, 0, 0, 0);
        }
        csq_part += __shfl_xor(csq_part, 16, 64);
        csq_part += __shfl_xor(csq_part, 32, 64);
        if (tt == 0 && q == 0) csqs[kglob] = csq_part;
#pragma unroll
        for (int r = 0; r < 4; ++r)
            Mw[(kt * 16 + q * 4 + r) * MW_P + tt * 16 + n] = acc[r];
    }
    __syncthreads();

    // --- softmax over k (lane = k); wave handles t = 4*wave..+3 ---
    {
        const float cq = csqs[lane];
        float sp = 0.f;
#pragma unroll
        for (int j = 0; j < 4; ++j) {
            int t = 4 * wave + j;
            float m     = Mw[lane * MW_P + t];
            float logit = -sc * (xsq[t] - 2.f * m + cq);
            float mx = logit;
#pragma unroll
            for (int off = 32; off >= 1; off >>= 1)
                mx = fmaxf(mx, __shfl_xor(mx, off, 64));
            float e = __expf(logit - mx);
            float s = e;
#pragma unroll
            for (int off = 32; off >= 1; off >>= 1)
                s += __shfl_xor(s, off, 64);
            float wv = e / s;
            if (t0 + t >= Tn) wv = 0.f;
            sp += wv;
            wl[lane * WL_P + t] = f2bf(wv);
        }
        spw[wave * 64 + lane] = sp;
    }
    __syncthreads();

    if (tid < 64) {
        float s = 0.f;
#pragma unroll
        for (int w = 0; w < 8; ++w) s += spw[w * 64 + tid];
        Sp[((size_t)b * Kn + tid) * NCH + ch] = s;
    }

    // --- pool: wave -> (k-tile = wave>>1, c-half = wave&1); K = 32 = CH ---
    {
        const int kt    = wave >> 1;
        const int chalf = (wave & 1) * 128;
        bf16x8 aF = *(const bf16x8*)(wl + (kt * 16 + n) * WL_P + q * 8);
        float* pb0 = part + ((size_t)(b * NCH + ch) * Kn + kt * 16 + q * 4) * Cn;
#pragma unroll
        for (int s = 0; s < 8; ++s) {
            int cc = chalf + s * 16;
            bf16x8 bF = *(const bf16x8*)(xc + (cc + n) * XC_P + q * 8);
            f32x4 acc = {0.f, 0.f, 0.f, 0.f};
            acc = __builtin_amdgcn_mfma_f32_16x16x32_bf16(aF, bF, acc, 0, 0, 0);
#pragma unroll
            for (int r = 0; r < 4; ++r)
                pb0[(size_t)r * Cn + cc + n] = acc[r];
        }
    }
}

// ---------------------------------------------------------------------------
// Finish: block per (b,k), 256 thr = c. Sum 32 chunk-partials, subtract
// codes*S, scale 1/T, l2-normalize over c.
// ---------------------------------------------------------------------------
__global__ __launch_bounds__(256) void lde_fin(
    const float* __restrict__ part,    // (B, NCH, K, C)
    const float* __restrict__ Sp,      // (B, K, NCH)
    const float* __restrict__ codes,   // (C, K)
    float* __restrict__ out)           // (B, K, C)
{
    const int b    = blockIdx.x >> 6;
    const int k    = blockIdx.x & 63;
    const int tid  = threadIdx.x;
    const int lane = tid & 63;
    const int wave = tid >> 6;

    __shared__ float red[4];
    __shared__ float Ss;

    if (wave == 0) {
        float s = (lane < NCH) ? Sp[((size_t)b * Kn + k) * NCH + lane] : 0.f;
#pragma unroll
        for (int off = 32; off >= 1; off >>= 1) s += __shfl_xor(s, off, 64);
        if (lane == 0) Ss = s;
    }
    __syncthreads();
    const float S = Ss;

    const int c = tid;
    const float* pb = part + (size_t)b * NCH * Kn * Cn + (size_t)k * Cn + c;
    float val = 0.f;
#pragma unroll
    for (int chn = 0; chn < NCH; ++chn) val += pb[(size_t)chn * Kn * Cn];

    float e = (val - codes[c * Kn + k] * S) * (1.0f / (float)Tn);

    float qq = e * e;
#pragma unroll
    for (int off = 32; off >= 1; off >>= 1) qq += __shfl_xor(qq, off, 64);
    if (lane == 0) red[wave] = qq;
    __syncthreads();
    float nn = sqrtf(red[0] + red[1] + red[2] + red[3]);

    out[((size_t)b * Kn + k) * Cn + c] = e / fmaxf(nn, 1e-12f);
}

extern "C" void kernel_launch(void* const* d_in, const int* in_sizes, int n_in,
                              void* d_out, int out_size, void* d_ws, size_t ws_size,
                              hipStream_t stream) {
    const float* x      = (const float*)d_in[0];   // (B, C, T) f32
    const float* codes  = (const float*)d_in[1];   // (C, K)    f32
    const float* scales = (const float*)d_in[2];   // (K)       f32
    float* out = (float*)d_out;                    // (B, K, C) f32

    char* ws = (char*)d_ws;
    float* part = (float*)ws;                      // 16 MB: (B, NCH, K, C) f32
    float* Sp   = (float*)(ws + (16u << 20));      // 64 KB: (B, K, NCH) f32

    lde_wp <<<Bn * NCH, 512, 0, stream>>>(x, codes, scales, part, Sp);
    lde_fin<<<Bn * Kn,  256, 0, stream>>>(part, Sp, codes, out);
}